// Round 12
// baseline (176.065 us; speedup 1.0000x reference)
//
#include <hip/hip_runtime.h>
#include <cstddef>

// Problem constants
#define Bsz 8
#define Nn  1024
#define Cc  512
#define Hh  8
#define Dd  64
#define EPSF 1e-6f

typedef __attribute__((ext_vector_type(8))) short short8;   // 8 bf16 (4 VGPRs)
typedef __attribute__((ext_vector_type(4))) float floatx4;  // MFMA accumulator

// round-to-nearest-even fp32 -> bf16 (bit pattern in a short)
static __device__ __forceinline__ short f2bf(float f) {
    union { float f; unsigned u; } v; v.f = f;
    unsigned r = (v.u + 0x7FFFu + ((v.u >> 16) & 1u)) >> 16;
    return (short)r;
}
static __device__ __forceinline__ float bf2f(short s) {
    union { unsigned u; float f; } v; v.u = ((unsigned)(unsigned short)s) << 16;
    return v.f;
}

// ---------------------------------------------------------------------------
// XOR-swizzled LDS tiles, linear 16B slots (lane-linear => global_load_lds ok).
// Tile = ROWS x (CHUNKS*8) bf16.  Slot s holds row r=s/CHUNKS, global chunk
// (s%CHUNKS)^(r&7).  Fragment read for row r, logical chunk lc is slot
// r*CHUNKS + (lc^(r&7)) -> bank-balanced ds_read_b128.
// ---------------------------------------------------------------------------
#define GLOAD_LDS16(gp, lp)                                              \
    __builtin_amdgcn_global_load_lds(                                    \
        (const __attribute__((address_space(1))) void*)(gp),             \
        (__attribute__((address_space(3))) void*)(lp), 16, 0, 0)

static __device__ __forceinline__
void stage_tile(short* __restrict__ lds, const short* __restrict__ src,
                int ldsrc, int tid, int CHUNKS, int SLOTS) {
    #pragma unroll
    for (int s = tid; s < SLOTS; s += 256) {
        int r = s / CHUNKS, cs = s % CHUNKS;
        int gc = cs ^ (r & 7);
        GLOAD_LDS16(&src[(size_t)r * ldsrc + gc * 8], &lds[s * 8]);
    }
}
static __device__ __forceinline__
short8 fragT(const short* __restrict__ lds, int CHUNKS, int r, int lc) {
    return *(const short8*)&lds[(r * CHUNKS + (lc ^ (r & 7))) * 8];
}

// ---------------------------------------------------------------------------
// Merged prep: blocks [0,2048) cvt x->bf16; [2048,2304) diffusion operator;
// [2304,2496) w_qkv^T; [2496,2560) w_out^T bf16; [2560,3072) mask->bf16.
// ---------------------------------------------------------------------------
__global__ __launch_bounds__(256)
void prep_all(const float* __restrict__ x, const float* __restrict__ mask,
              const float* __restrict__ wq, const float* __restrict__ wo,
              short* __restrict__ xb, short* __restrict__ Ad,
              short* __restrict__ wqT, short* __restrict__ woT,
              short* __restrict__ mbf) {
    __shared__ float t[64][65];
    const int tid = threadIdx.x;
    const int bid = blockIdx.x;

    if (bid < 2048) {                       // x -> bf16, 8 elems/thread
        int idx = bid * 256 + tid;
        const float* s = &x[(size_t)idx * 8];
        union { short h[8]; int4 v; } u;
        #pragma unroll
        for (int j = 0; j < 8; j++) u.h[j] = f2bf(s[j]);
        *(int4*)&xb[(size_t)idx * 8] = u.v;
        return;
    }
    if (bid < 2304) {                       // Ad[n][m] = bf16(I + 0.1*mask^T)
        int idx = bid - 2048;
        const int n0 = (idx & 15) * 64, m0 = (idx >> 4) * 64;
        #pragma unroll
        for (int i = 0; i < 4; i++) {
            int k = i * 256 + tid;
            int r = k >> 4, c4 = (k & 15) * 4;
            *(float4*)&t[r][c4] = *(const float4*)&mask[(size_t)(m0 + r) * Nn + n0 + c4];
        }
        __syncthreads();
        #pragma unroll
        for (int i = 0; i < 4; i++) {
            int k = i * 256 + tid;
            int rr = k >> 4, c4 = (k & 15) * 4;
            union { short h[4]; int2 v; } u;
            #pragma unroll
            for (int j = 0; j < 4; j++) {
                int mm = c4 + j;
                float v = 0.1f * t[mm][rr] + ((n0 + rr) == (m0 + mm) ? 1.0f : 0.0f);
                u.h[j] = f2bf(v);
            }
            *(int2*)&Ad[(size_t)(n0 + rr) * Nn + m0 + c4] = u.v;
        }
        return;
    }
    if (bid < 2496) {                       // wqT[n][k] = bf16(wq[k][n])
        int idx = bid - 2304;
        const int n0 = (idx % 24) * 64, k0 = (idx / 24) * 64;
        #pragma unroll
        for (int i = 0; i < 4; i++) {
            int k = i * 256 + tid;
            int r = k >> 4, c4 = (k & 15) * 4;
            *(float4*)&t[r][c4] = *(const float4*)&wq[(size_t)(k0 + r) * 1536 + n0 + c4];
        }
        __syncthreads();
        #pragma unroll
        for (int i = 0; i < 4; i++) {
            int k = i * 256 + tid;
            int rr = k >> 4, c4 = (k & 15) * 4;
            union { short h[4]; int2 v; } u;
            #pragma unroll
            for (int j = 0; j < 4; j++) u.h[j] = f2bf(t[c4 + j][rr]);
            *(int2*)&wqT[(size_t)(n0 + rr) * 512 + k0 + c4] = u.v;
        }
        return;
    }
    if (bid < 2560) {                        // woT[n][k] = bf16(wo[k][n])
        int idx = bid - 2496;
        const int n0 = (idx & 7) * 64, k0 = (idx >> 3) * 64;
        #pragma unroll
        for (int i = 0; i < 4; i++) {
            int k = i * 256 + tid;
            int r = k >> 4, c4 = (k & 15) * 4;
            *(float4*)&t[r][c4] = *(const float4*)&wo[(size_t)(k0 + r) * 512 + n0 + c4];
        }
        __syncthreads();
        #pragma unroll
        for (int i = 0; i < 4; i++) {
            int k = i * 256 + tid;
            int rr = k >> 4, c4 = (k & 15) * 4;
            union { short h[4]; int2 v; } u;
            #pragma unroll
            for (int j = 0; j < 4; j++) u.h[j] = f2bf(t[c4 + j][rr]);
            *(int2*)&woT[(size_t)(n0 + rr) * 512 + k0 + c4] = u.v;
        }
        return;
    }
    {                                        // mask -> bf16 (original [n][m])
        int idx = (bid - 2560) * 256 + tid;  // 8 elems/thread, 1M total
        const float* s = &mask[(size_t)idx * 8];
        union { short h[8]; int4 v; } u;
        #pragma unroll
        for (int j = 0; j < 8; j++) u.h[j] = f2bf(s[j]);
        *(int4*)&mbf[(size_t)idx * 8] = u.v;
    }
}

// ---------------------------------------------------------------------------
// GEMM1: qkv = xb[8192][512] @ wqT^T, relu+eps on cols<1024.
// Epilogue: LDS transpose, writes qT/kT/vT[b][c][m] bf16 (B-operand layout).
// BK stays 64: grid 768 at 34.8 KB = 3 blocks/CU single-round; 64 KB would
// force 2-round dispatch (r6 trap).
// ---------------------------------------------------------------------------
__global__ __launch_bounds__(256)
void gemm_qkv(const short* __restrict__ xb, const short* __restrict__ wqT,
              short* __restrict__ qT, short* __restrict__ kT,
              short* __restrict__ vT) {
    __shared__ short smem[17408];             // 34816 B
    short* As = smem;
    short* Bs = smem + 8192;

    const int tid = threadIdx.x;
    const int m0 = blockIdx.y * 128;
    const int n0 = blockIdx.x * 128;
    const int wave = tid >> 6, lane = tid & 63;
    const int quad = lane >> 4, l16 = lane & 15;
    const int wm = (wave >> 1) * 64, wn = (wave & 1) * 64;

    floatx4 acc[4][4];
    #pragma unroll
    for (int i = 0; i < 4; i++)
        #pragma unroll
        for (int j = 0; j < 4; j++) acc[i][j] = (floatx4){0.f, 0.f, 0.f, 0.f};

    const short* Ab = xb  + (size_t)m0 * 512;
    const short* Bb = wqT + (size_t)n0 * 512;

    for (int k0 = 0; k0 < 512; k0 += 64) {
        __syncthreads();
        stage_tile(As, Ab + k0, 512, tid, 8, 1024);
        stage_tile(Bs, Bb + k0, 512, tid, 8, 1024);
        __syncthreads();
        #pragma unroll
        for (int kh = 0; kh < 2; kh++) {
            short8 a[4], b[4];
            #pragma unroll
            for (int i = 0; i < 4; i++) a[i] = fragT(As, 8, wm + i * 16 + l16, kh * 4 + quad);
            #pragma unroll
            for (int i = 0; i < 4; i++) b[i] = fragT(Bs, 8, wn + i * 16 + l16, kh * 4 + quad);
            #pragma unroll
            for (int mi = 0; mi < 4; mi++)
                #pragma unroll
                for (int ni = 0; ni < 4; ni++)
                    acc[mi][ni] = __builtin_amdgcn_mfma_f32_16x16x32_bf16(
                        a[mi], b[ni], acc[mi][ni], 0, 0, 0);
        }
    }

    __syncthreads();
    short* Tt = smem;                          // [128 cols][136]
    const int doRelu = (n0 < 1024);
    #pragma unroll
    for (int mi = 0; mi < 4; mi++)
        #pragma unroll
        for (int ni = 0; ni < 4; ni++)
            #pragma unroll
            for (int r = 0; r < 4; r++) {
                float v = acc[mi][ni][r];
                if (doRelu) v = fmaxf(v, 0.0f) + EPSF;
                int nl = wn + ni * 16 + l16;
                int ml = wm + mi * 16 + quad * 4 + r;
                Tt[nl * 136 + ml] = f2bf(v);
            }
    __syncthreads();

    const int b = m0 >> 10, m_in = m0 & 1023;
    int row = tid >> 1, half = tid & 1;
    int cg = n0 + row;
    int part = cg >> 9, ci = cg & 511;
    short* base = (part == 0) ? qT : (part == 1) ? kT : vT;
    short* dst = base + ((size_t)b * 512 + ci) * 1024 + m_in + half * 64;
    const short* srcl = &Tt[row * 136 + half * 64];
    #pragma unroll
    for (int i = 0; i < 8; i++)     // 8 x int4 = full 64-short half-row
        *(int4*)&dst[i * 8] = *(const int4*)&srcl[i * 8];
}

// ---------------------------------------------------------------------------
// Diffusion GEMM: qd[b][n][c] = sum_m Ad[n][m] * q[b][m][c]  (BT = qT)
// BK=128: two 64-K sub-tiles per barrier pair (halves barrier-drain count).
// LDS 64 KB -> 2 blocks/CU capacity == grid 512 = 2/CU grid-limited: free.
// ---------------------------------------------------------------------------
__global__ __launch_bounds__(256)
void gemm_diff(const short* __restrict__ Ad, const short* __restrict__ qT,
               const short* __restrict__ kT, short* __restrict__ qd,
               short* __restrict__ kd) {
    __shared__ short smem[32768];     // 64 KB
    short* As0 = smem;                // 128x64 each
    short* As1 = smem + 8192;
    short* Bs0 = smem + 16384;
    short* Bs1 = smem + 24576;

    const int tid = threadIdx.x;
    const int z = blockIdx.z, b = z >> 1, part = z & 1;
    const short* BTb = (part ? kT : qT) + (size_t)b * 512 * 1024;
    short* outb = (part ? kd : qd) + (size_t)b * 1024 * 512;

    const int r0 = blockIdx.y * 128;
    const int c0 = blockIdx.x * 128;
    const int wave = tid >> 6, lane = tid & 63;
    const int quad = lane >> 4, l16 = lane & 15;
    const int wm = (wave >> 1) * 64, wn = (wave & 1) * 64;

    floatx4 acc[4][4];
    #pragma unroll
    for (int i = 0; i < 4; i++)
        #pragma unroll
        for (int j = 0; j < 4; j++) acc[i][j] = (floatx4){0.f, 0.f, 0.f, 0.f};

    const short* Ab = Ad  + (size_t)r0 * 1024;
    const short* Bb = BTb + (size_t)c0 * 1024;

    for (int k0 = 0; k0 < 1024; k0 += 128) {
        __syncthreads();
        stage_tile(As0, Ab + k0,      1024, tid, 8, 1024);
        stage_tile(As1, Ab + k0 + 64, 1024, tid, 8, 1024);
        stage_tile(Bs0, Bb + k0,      1024, tid, 8, 1024);
        stage_tile(Bs1, Bb + k0 + 64, 1024, tid, 8, 1024);
        __syncthreads();
        #pragma unroll
        for (int hf = 0; hf < 2; hf++) {
            const short* Ah = hf ? As1 : As0;
            const short* Bh = hf ? Bs1 : Bs0;
            #pragma unroll
            for (int kh = 0; kh < 2; kh++) {
                short8 a[4], b2[4];
                #pragma unroll
                for (int i = 0; i < 4; i++) a[i]  = fragT(Ah, 8, wm + i * 16 + l16, kh * 4 + quad);
                #pragma unroll
                for (int i = 0; i < 4; i++) b2[i] = fragT(Bh, 8, wn + i * 16 + l16, kh * 4 + quad);
                #pragma unroll
                for (int mi = 0; mi < 4; mi++)
                    #pragma unroll
                    for (int ni = 0; ni < 4; ni++)
                        acc[mi][ni] = __builtin_amdgcn_mfma_f32_16x16x32_bf16(
                            a[mi], b2[ni], acc[mi][ni], 0, 0, 0);
            }
        }
    }

    #pragma unroll
    for (int mi = 0; mi < 4; mi++)
        #pragma unroll
        for (int r = 0; r < 4; r++) {
            int n = r0 + wm + mi * 16 + quad * 4 + r;
            #pragma unroll
            for (int ni = 0; ni < 4; ni++) {
                int c = c0 + wn + ni * 16 + l16;
                outb[(size_t)n * 512 + c] = f2bf(acc[mi][ni][r]);
            }
        }
}

// ---------------------------------------------------------------------------
// Masked linear attention (MFMA bf16, flash-style), v7 (r10/r11-verified):
// S^T phase A, mask staged to LDS as bf16 via async DMA (zero K-loop VMEM).
// ---------------------------------------------------------------------------
__global__ __launch_bounds__(256)
void attn_mfma(const short* __restrict__ qd, const short* __restrict__ kd,
               const short* __restrict__ vTg, const short* __restrict__ mbf,
               short* __restrict__ abf) {
    __shared__ short qs[8192];   // 128 n-rows x 64 c (8 chunks)
    __shared__ short ks[4096];   //  64 m-rows x 64 c (8 chunks)
    __shared__ short vt[4096];   //  64 d-rows x 64 m (8 chunks)
    __shared__ short ss[8192];   // 128 n-rows x 64 m (8 chunks, wave-private rows)
    __shared__ short ms[8192];   // 128 n-rows x 64 m mask tile (bf16, same swizzle)

    const int tid = threadIdx.x;
    const int bh = blockIdx.y;
    const int b = bh >> 3, h = bh & 7;
    const int n0 = blockIdx.x * 128;

    const int wave = tid >> 6, lane = tid & 63;
    const int quad = lane >> 4, l16 = lane & 15;

    const short* Qb = qd + ((size_t)b * Nn + n0) * Cc + h * Dd;        // stride Cc
    const short* Kb = kd + (size_t)b * Nn * Cc + h * Dd;               // stride Cc
    const short* Vb = vTg + ((size_t)b * Cc + h * Dd) * Nn;            // stride Nn
    const short* Mb = mbf + (size_t)n0 * Nn;                           // stride Nn

    stage_tile(qs, Qb, Cc, tid, 8, 1024);
    __syncthreads();                          // qs resident (vmcnt drained)
    short8 aT[2][2];                          // Q-frags (B-operand of S^T mfma)
    #pragma unroll
    for (int t = 0; t < 2; t++) {
        aT[t][0] = fragT(qs, 8, wave * 32 + t * 16 + l16, quad);
        aT[t][1] = fragT(qs, 8, wave * 32 + t * 16 + l16, 4 + quad);
    }

    float dreg[2] = {0.f, 0.f};               // partial denom for n-row = l16 (per t)
    floatx4 nacc[2][4];
    #pragma unroll
    for (int t = 0; t < 2; t++)
        #pragma unroll
        for (int i = 0; i < 4; i++) nacc[t][i] = (floatx4){0.f, 0.f, 0.f, 0.f};

    const int ssrow[2] = { wave * 32 + l16, wave * 32 + 16 + l16 };

    for (int m0 = 0; m0 < Nn; m0 += 64) {
        __syncthreads();                      // prior chunk's readers done
        stage_tile(ks, Kb + (size_t)m0 * Cc, Cc, tid, 8, 512);
        stage_tile(vt, Vb + m0, Nn, tid, 8, 512);
        stage_tile(ms, Mb + m0, Nn, tid, 8, 1024);   // mask tile, async DMA
        __syncthreads();                      // staged data visible

        // phase A: S^T = K Q^T; C: col=l16=n, row=quad*4+r=m
        #pragma unroll
        for (int mt = 0; mt < 4; mt++) {
            const short8 k0f = fragT(ks, 8, mt * 16 + l16, quad);
            const short8 k1f = fragT(ks, 8, mt * 16 + l16, 4 + quad);
            #pragma unroll
            for (int t = 0; t < 2; t++) {
                floatx4 s = (floatx4){0.f, 0.f, 0.f, 0.f};
                s = __builtin_amdgcn_mfma_f32_16x16x32_bf16(k0f, aT[t][0], s, 0, 0, 0);
                s = __builtin_amdgcn_mfma_f32_16x16x32_bf16(k1f, aT[t][1], s, 0, 0, 0);
                const int row = ssrow[t];
                const int c = mt * 16 + quad * 4;
                const int off = (row * 8 + ((c >> 3) ^ (row & 7))) * 8 + (c & 7);
                union { short h[4]; int2 v; } mk;
                mk.v = *(const int2*)&ms[off];          // ds_read_b64, no VMEM
                float sv0 = s[0] * bf2f(mk.h[0]);
                float sv1 = s[1] * bf2f(mk.h[1]);
                float sv2 = s[2] * bf2f(mk.h[2]);
                float sv3 = s[3] * bf2f(mk.h[3]);
                dreg[t] += (sv0 + sv1) + (sv2 + sv3);
                union { short h[4]; int2 v; } pk;
                pk.h[0] = f2bf(sv0); pk.h[1] = f2bf(sv1);
                pk.h[2] = f2bf(sv2); pk.h[3] = f2bf(sv3);
                *(int2*)&ss[off] = pk.v;                // ds_write_b64
            }
        }
        // no barrier: each wave reads exactly the ss rows it wrote
        // (within-wave in-order LDS + compiler lgkmcnt suffices)

        // phase B: num += P @ V.  V-frags shared across both n-tiles.
        short8 p[2][2];
        #pragma unroll
        for (int t = 0; t < 2; t++) {
            p[t][0] = fragT(ss, 8, wave * 32 + t * 16 + l16, quad);
            p[t][1] = fragT(ss, 8, wave * 32 + t * 16 + l16, 4 + quad);
        }
        #pragma unroll
        for (int dt = 0; dt < 4; dt++) {
            const short8 v0 = fragT(vt, 8, dt * 16 + l16, quad);
            const short8 v1 = fragT(vt, 8, dt * 16 + l16, 4 + quad);
            #pragma unroll
            for (int t = 0; t < 2; t++) {
                nacc[t][dt] = __builtin_amdgcn_mfma_f32_16x16x32_bf16(p[t][0], v0, nacc[t][dt], 0, 0, 0);
                nacc[t][dt] = __builtin_amdgcn_mfma_f32_16x16x32_bf16(p[t][1], v1, nacc[t][dt], 0, 0, 0);
            }
        }
    }

    // denom: cross-quad reduce (lanes sharing l16), then per-lane broadcast
    #pragma unroll
    for (int t = 0; t < 2; t++) {
        dreg[t] += __shfl_xor(dreg[t], 16, 64);
        dreg[t] += __shfl_xor(dreg[t], 32, 64);
    }

    #pragma unroll
    for (int t = 0; t < 2; t++)
        #pragma unroll
        for (int r = 0; r < 4; r++) {
            int nloc = quad * 4 + r;          // n within this 16-tile
            float den = __shfl(dreg[t], nloc, 64);
            int n = n0 + wave * 32 + t * 16 + nloc;
            float zr = 1.0f / (den + EPSF);
            #pragma unroll
            for (int dt = 0; dt < 4; dt++) {
                size_t o = ((size_t)b * Nn + n) * Cc + h * Dd + dt * 16 + l16;
                abf[o] = f2bf(nacc[t][dt][r] * zr);
            }
        }
}

// ---------------------------------------------------------------------------
// Output GEMM (single bf16 pass): out = A@W^T + bias (fp32 accumulate).
// BK=128 (two sub-tiles per barrier pair).  LDS 48 KB; grid 512 = 2/CU.
// ---------------------------------------------------------------------------
__global__ __launch_bounds__(256)
void gemm_out(const short* __restrict__ abf, const short* __restrict__ woT,
              const float* __restrict__ bias, float* __restrict__ out) {
    __shared__ short smem[24576];      // 48 KB
    short* As0 = smem;                 // 64x64 each
    short* As1 = smem + 4096;
    short* Bs0 = smem + 8192;          // 128x64 each
    short* Bs1 = smem + 16384;

    const int tid = threadIdx.x;
    const int m0 = blockIdx.y * 64;
    const int n0 = blockIdx.x * 128;
    const int wave = tid >> 6, lane = tid & 63;
    const int quad = lane >> 4, l16 = lane & 15;
    const int wm = (wave >> 1) * 32, wn = (wave & 1) * 64;

    floatx4 acc[2][4];
    #pragma unroll
    for (int i = 0; i < 2; i++)
        #pragma unroll
        for (int j = 0; j < 4; j++) acc[i][j] = (floatx4){0.f, 0.f, 0.f, 0.f};

    const short* Ab = abf + (size_t)m0 * 512;
    const short* Bb = woT + (size_t)n0 * 512;

    for (int k0 = 0; k0 < 512; k0 += 128) {
        __syncthreads();
        stage_tile(As0, Ab + k0,      512, tid, 8, 512);
        stage_tile(As1, Ab + k0 + 64, 512, tid, 8, 512);
        stage_tile(Bs0, Bb + k0,      512, tid, 8, 1024);
        stage_tile(Bs1, Bb + k0 + 64, 512, tid, 8, 1024);
        __syncthreads();
        #pragma unroll
        for (int hf = 0; hf < 2; hf++) {
            const short* Ah = hf ? As1 : As0;
            const short* Bh = hf ? Bs1 : Bs0;
            #pragma unroll
            for (int kh = 0; kh < 2; kh++) {
                short8 a[2], b[4];
                #pragma unroll
                for (int i = 0; i < 2; i++)
                    a[i] = fragT(Ah, 8, wm + i * 16 + l16, kh * 4 + quad);
                #pragma unroll
                for (int i = 0; i < 4; i++)
                    b[i] = fragT(Bh, 8, wn + i * 16 + l16, kh * 4 + quad);
                #pragma unroll
                for (int mi = 0; mi < 2; mi++)
                    #pragma unroll
                    for (int ni = 0; ni < 4; ni++)
                        acc[mi][ni] = __builtin_amdgcn_mfma_f32_16x16x32_bf16(
                            a[mi], b[ni], acc[mi][ni], 0, 0, 0);
            }
        }
    }

    #pragma unroll
    for (int mi = 0; mi < 2; mi++)
        #pragma unroll
        for (int r = 0; r < 4; r++) {
            int m = m0 + wm + mi * 16 + quad * 4 + r;
            #pragma unroll
            for (int ni = 0; ni < 4; ni++) {
                int n = n0 + wn + ni * 16 + l16;
                out[(size_t)m * 512 + n] = acc[mi][ni][r] + bias[n];
            }
        }
}

// ---------------------------------------------------------------------------
extern "C" void kernel_launch(void* const* d_in, const int* in_sizes, int n_in,
                              void* d_out, int out_size, void* d_ws, size_t ws_size,
                              hipStream_t stream) {
    const float* x     = (const float*)d_in[0];
    const float* mask  = (const float*)d_in[1];
    const float* w_qkv = (const float*)d_in[2];
    const float* w_out = (const float*)d_in[3];
    const float* b_out = (const float*)d_in[4];
    float* out = (float*)d_out;

    char* p = (char*)d_ws;
    short* xb  = (short*)p; p += 8388608;      // [8192][512]
    short* wqT = (short*)p; p += 1572864;      // [1536][512]
    short* Ad  = (short*)p; p += 2097152;      // [1024][1024]
    short* woT = (short*)p; p += 524288;       // [512][512]
    short* mbf = (short*)p; p += 2097152;      // [1024][1024] bf16 mask
    short* qT  = (short*)p; p += 8388608;      // [b][512][1024]
    short* kT  = (short*)p; p += 8388608;
    short* vT  = (short*)p; p += 8388608;
    short* qd  = (short*)p; p += 8388608;      // [b][1024][512]
    short* kd  = (short*)p; p += 8388608;
    short* abf = (short*)p; p += 8388608;      // [8192][512] attn out bf16

    dim3 blk(256);

    prep_all  <<<3072, blk, 0, stream>>>(x, mask, w_qkv, w_out,
                                         xb, Ad, wqT, woT, mbf);
    gemm_qkv  <<<dim3(12, 64), blk, 0, stream>>>(xb, wqT, qT, kT, vT);
    gemm_diff <<<dim3(4, 8, 16), blk, 0, stream>>>(Ad, qT, kT, qd, kd);
    attn_mfma <<<dim3(8, 64),  blk, 0, stream>>>(qd, kd, vT, mbf, abf);
    gemm_out  <<<dim3(4, 128), blk, 0, stream>>>(abf, woT, b_out, out);
}

// Round 13
// 169.824 us; speedup vs baseline: 1.0367x; 1.0367x over previous
//
#include <hip/hip_runtime.h>
#include <cstddef>

// Problem constants
#define Bsz 8
#define Nn  1024
#define Cc  512
#define Hh  8
#define Dd  64
#define EPSF 1e-6f

typedef __attribute__((ext_vector_type(8))) short short8;   // 8 bf16 (4 VGPRs)
typedef __attribute__((ext_vector_type(4))) float floatx4;  // MFMA accumulator

// round-to-nearest-even fp32 -> bf16 (bit pattern in a short)
static __device__ __forceinline__ short f2bf(float f) {
    union { float f; unsigned u; } v; v.f = f;
    unsigned r = (v.u + 0x7FFFu + ((v.u >> 16) & 1u)) >> 16;
    return (short)r;
}
static __device__ __forceinline__ float bf2f(short s) {
    union { unsigned u; float f; } v; v.u = ((unsigned)(unsigned short)s) << 16;
    return v.f;
}

// ---------------------------------------------------------------------------
// XOR-swizzled LDS tiles, linear 16B slots (lane-linear => global_load_lds ok).
// Tile = ROWS x (CHUNKS*8) bf16.  Slot s holds row r=s/CHUNKS, global chunk
// (s%CHUNKS)^(r&7).  Fragment read for row r, logical chunk lc is slot
// r*CHUNKS + (lc^(r&7)) -> bank-balanced ds_read_b128.
// ---------------------------------------------------------------------------
#define GLOAD_LDS16(gp, lp)                                              \
    __builtin_amdgcn_global_load_lds(                                    \
        (const __attribute__((address_space(1))) void*)(gp),             \
        (__attribute__((address_space(3))) void*)(lp), 16, 0, 0)

static __device__ __forceinline__
void stage_tile(short* __restrict__ lds, const short* __restrict__ src,
                int ldsrc, int tid, int CHUNKS, int SLOTS) {
    #pragma unroll
    for (int s = tid; s < SLOTS; s += 256) {
        int r = s / CHUNKS, cs = s % CHUNKS;
        int gc = cs ^ (r & 7);
        GLOAD_LDS16(&src[(size_t)r * ldsrc + gc * 8], &lds[s * 8]);
    }
}
static __device__ __forceinline__
short8 fragT(const short* __restrict__ lds, int CHUNKS, int r, int lc) {
    return *(const short8*)&lds[(r * CHUNKS + (lc ^ (r & 7))) * 8];
}

// ---------------------------------------------------------------------------
// Merged prep: blocks [0,2048) cvt x->bf16; [2048,2304) diffusion operator;
// [2304,2496) w_qkv^T; [2496,2560) w_out^T bf16; [2560,3072) mask->bf16.
// ---------------------------------------------------------------------------
__global__ __launch_bounds__(256)
void prep_all(const float* __restrict__ x, const float* __restrict__ mask,
              const float* __restrict__ wq, const float* __restrict__ wo,
              short* __restrict__ xb, short* __restrict__ Ad,
              short* __restrict__ wqT, short* __restrict__ woT,
              short* __restrict__ mbf) {
    __shared__ float t[64][65];
    const int tid = threadIdx.x;
    const int bid = blockIdx.x;

    if (bid < 2048) {                       // x -> bf16, 8 elems/thread
        int idx = bid * 256 + tid;
        const float* s = &x[(size_t)idx * 8];
        union { short h[8]; int4 v; } u;
        #pragma unroll
        for (int j = 0; j < 8; j++) u.h[j] = f2bf(s[j]);
        *(int4*)&xb[(size_t)idx * 8] = u.v;
        return;
    }
    if (bid < 2304) {                       // Ad[n][m] = bf16(I + 0.1*mask^T)
        int idx = bid - 2048;
        const int n0 = (idx & 15) * 64, m0 = (idx >> 4) * 64;
        #pragma unroll
        for (int i = 0; i < 4; i++) {
            int k = i * 256 + tid;
            int r = k >> 4, c4 = (k & 15) * 4;
            *(float4*)&t[r][c4] = *(const float4*)&mask[(size_t)(m0 + r) * Nn + n0 + c4];
        }
        __syncthreads();
        #pragma unroll
        for (int i = 0; i < 4; i++) {
            int k = i * 256 + tid;
            int rr = k >> 4, c4 = (k & 15) * 4;
            union { short h[4]; int2 v; } u;
            #pragma unroll
            for (int j = 0; j < 4; j++) {
                int mm = c4 + j;
                float v = 0.1f * t[mm][rr] + ((n0 + rr) == (m0 + mm) ? 1.0f : 0.0f);
                u.h[j] = f2bf(v);
            }
            *(int2*)&Ad[(size_t)(n0 + rr) * Nn + m0 + c4] = u.v;
        }
        return;
    }
    if (bid < 2496) {                       // wqT[n][k] = bf16(wq[k][n])
        int idx = bid - 2304;
        const int n0 = (idx % 24) * 64, k0 = (idx / 24) * 64;
        #pragma unroll
        for (int i = 0; i < 4; i++) {
            int k = i * 256 + tid;
            int r = k >> 4, c4 = (k & 15) * 4;
            *(float4*)&t[r][c4] = *(const float4*)&wq[(size_t)(k0 + r) * 1536 + n0 + c4];
        }
        __syncthreads();
        #pragma unroll
        for (int i = 0; i < 4; i++) {
            int k = i * 256 + tid;
            int rr = k >> 4, c4 = (k & 15) * 4;
            union { short h[4]; int2 v; } u;
            #pragma unroll
            for (int j = 0; j < 4; j++) u.h[j] = f2bf(t[c4 + j][rr]);
            *(int2*)&wqT[(size_t)(n0 + rr) * 512 + k0 + c4] = u.v;
        }
        return;
    }
    if (bid < 2560) {                        // woT[n][k] = bf16(wo[k][n])
        int idx = bid - 2496;
        const int n0 = (idx & 7) * 64, k0 = (idx >> 3) * 64;
        #pragma unroll
        for (int i = 0; i < 4; i++) {
            int k = i * 256 + tid;
            int r = k >> 4, c4 = (k & 15) * 4;
            *(float4*)&t[r][c4] = *(const float4*)&wo[(size_t)(k0 + r) * 512 + n0 + c4];
        }
        __syncthreads();
        #pragma unroll
        for (int i = 0; i < 4; i++) {
            int k = i * 256 + tid;
            int rr = k >> 4, c4 = (k & 15) * 4;
            union { short h[4]; int2 v; } u;
            #pragma unroll
            for (int j = 0; j < 4; j++) u.h[j] = f2bf(t[c4 + j][rr]);
            *(int2*)&woT[(size_t)(n0 + rr) * 512 + k0 + c4] = u.v;
        }
        return;
    }
    {                                        // mask -> bf16 (original [n][m])
        int idx = (bid - 2560) * 256 + tid;  // 8 elems/thread, 1M total
        const float* s = &mask[(size_t)idx * 8];
        union { short h[8]; int4 v; } u;
        #pragma unroll
        for (int j = 0; j < 8; j++) u.h[j] = f2bf(s[j]);
        *(int4*)&mbf[(size_t)idx * 8] = u.v;
    }
}

// ---------------------------------------------------------------------------
// GEMM1: qkv = xb[8192][512] @ wqT^T, relu+eps on cols<1024.  BK=64.
// XCD swizzle: m0 on blockIdx.x so the 12 blocks sharing an xb slice
// colocate per-XCD (linear%8 == m0-index%8).
// ---------------------------------------------------------------------------
__global__ __launch_bounds__(256)
void gemm_qkv(const short* __restrict__ xb, const short* __restrict__ wqT,
              short* __restrict__ qT, short* __restrict__ kT,
              short* __restrict__ vT) {
    __shared__ short smem[17408];             // 34816 B
    short* As = smem;
    short* Bs = smem + 8192;

    const int tid = threadIdx.x;
    const int m0 = blockIdx.x * 128;          // swizzled: m on x
    const int n0 = blockIdx.y * 128;
    const int wave = tid >> 6, lane = tid & 63;
    const int quad = lane >> 4, l16 = lane & 15;
    const int wm = (wave >> 1) * 64, wn = (wave & 1) * 64;

    floatx4 acc[4][4];
    #pragma unroll
    for (int i = 0; i < 4; i++)
        #pragma unroll
        for (int j = 0; j < 4; j++) acc[i][j] = (floatx4){0.f, 0.f, 0.f, 0.f};

    const short* Ab = xb  + (size_t)m0 * 512;
    const short* Bb = wqT + (size_t)n0 * 512;

    for (int k0 = 0; k0 < 512; k0 += 64) {
        __syncthreads();
        stage_tile(As, Ab + k0, 512, tid, 8, 1024);
        stage_tile(Bs, Bb + k0, 512, tid, 8, 1024);
        __syncthreads();
        #pragma unroll
        for (int kh = 0; kh < 2; kh++) {
            short8 a[4], b[4];
            #pragma unroll
            for (int i = 0; i < 4; i++) a[i] = fragT(As, 8, wm + i * 16 + l16, kh * 4 + quad);
            #pragma unroll
            for (int i = 0; i < 4; i++) b[i] = fragT(Bs, 8, wn + i * 16 + l16, kh * 4 + quad);
            #pragma unroll
            for (int mi = 0; mi < 4; mi++)
                #pragma unroll
                for (int ni = 0; ni < 4; ni++)
                    acc[mi][ni] = __builtin_amdgcn_mfma_f32_16x16x32_bf16(
                        a[mi], b[ni], acc[mi][ni], 0, 0, 0);
        }
    }

    __syncthreads();
    short* Tt = smem;                          // [128 cols][136]
    const int doRelu = (n0 < 1024);
    #pragma unroll
    for (int mi = 0; mi < 4; mi++)
        #pragma unroll
        for (int ni = 0; ni < 4; ni++)
            #pragma unroll
            for (int r = 0; r < 4; r++) {
                float v = acc[mi][ni][r];
                if (doRelu) v = fmaxf(v, 0.0f) + EPSF;
                int nl = wn + ni * 16 + l16;
                int ml = wm + mi * 16 + quad * 4 + r;
                Tt[nl * 136 + ml] = f2bf(v);
            }
    __syncthreads();

    const int b = m0 >> 10, m_in = m0 & 1023;
    int row = tid >> 1, half = tid & 1;
    int cg = n0 + row;
    int part = cg >> 9, ci = cg & 511;
    short* base = (part == 0) ? qT : (part == 1) ? kT : vT;
    short* dst = base + ((size_t)b * 512 + ci) * 1024 + m_in + half * 64;
    const short* srcl = &Tt[row * 136 + half * 64];
    #pragma unroll
    for (int i = 0; i < 8; i++)     // 8 x int4 = full 64-short half-row
        *(int4*)&dst[i * 8] = *(const int4*)&srcl[i * 8];
}

// ---------------------------------------------------------------------------
// Diffusion GEMM: qd[b][n][c] = sum_m Ad[n][m] * q[b][m][c]  (BT = qT)
// BK=64 (r12 BK=128 regressed).  XCD swizzle: z (batch-part) on blockIdx.x
// so the 32 blocks sharing one BTb colocate per-XCD.
// ---------------------------------------------------------------------------
__global__ __launch_bounds__(256)
void gemm_diff(const short* __restrict__ Ad, const short* __restrict__ qT,
               const short* __restrict__ kT, short* __restrict__ qd,
               short* __restrict__ kd) {
    __shared__ short smem[16384];
    short* As = smem;
    short* Bs = smem + 8192;

    const int tid = threadIdx.x;
    const int z = blockIdx.x, b = z >> 1, part = z & 1;   // swizzled: z on x
    const short* BTb = (part ? kT : qT) + (size_t)b * 512 * 1024;
    short* outb = (part ? kd : qd) + (size_t)b * 1024 * 512;

    const int c0 = blockIdx.y * 128;
    const int r0 = blockIdx.z * 128;
    const int wave = tid >> 6, lane = tid & 63;
    const int quad = lane >> 4, l16 = lane & 15;
    const int wm = (wave >> 1) * 64, wn = (wave & 1) * 64;

    floatx4 acc[4][4];
    #pragma unroll
    for (int i = 0; i < 4; i++)
        #pragma unroll
        for (int j = 0; j < 4; j++) acc[i][j] = (floatx4){0.f, 0.f, 0.f, 0.f};

    const short* Ab = Ad  + (size_t)r0 * 1024;
    const short* Bb = BTb + (size_t)c0 * 1024;

    for (int k0 = 0; k0 < 1024; k0 += 64) {
        __syncthreads();
        stage_tile(As, Ab + k0, 1024, tid, 8, 1024);
        stage_tile(Bs, Bb + k0, 1024, tid, 8, 1024);
        __syncthreads();
        #pragma unroll
        for (int kh = 0; kh < 2; kh++) {
            short8 a[4], b2[4];
            #pragma unroll
            for (int i = 0; i < 4; i++) a[i]  = fragT(As, 8, wm + i * 16 + l16, kh * 4 + quad);
            #pragma unroll
            for (int i = 0; i < 4; i++) b2[i] = fragT(Bs, 8, wn + i * 16 + l16, kh * 4 + quad);
            #pragma unroll
            for (int mi = 0; mi < 4; mi++)
                #pragma unroll
                for (int ni = 0; ni < 4; ni++)
                    acc[mi][ni] = __builtin_amdgcn_mfma_f32_16x16x32_bf16(
                        a[mi], b2[ni], acc[mi][ni], 0, 0, 0);
        }
    }

    #pragma unroll
    for (int mi = 0; mi < 4; mi++)
        #pragma unroll
        for (int r = 0; r < 4; r++) {
            int n = r0 + wm + mi * 16 + quad * 4 + r;
            #pragma unroll
            for (int ni = 0; ni < 4; ni++) {
                int c = c0 + wn + ni * 16 + l16;
                outb[(size_t)n * 512 + c] = f2bf(acc[mi][ni][r]);
            }
        }
}

// ---------------------------------------------------------------------------
// Masked linear attention (MFMA bf16, flash-style), v8:
// r11-verified body.  XCD swizzle: bh on blockIdx.x so the 8 n0-blocks
// sharing one (b,h)'s K/V land on the same XCD (linear%8 == bh%8) --
// r11 FETCH was 72 MB vs 26 MB unique (K/V replicated across 8 XCD L2s).
// ---------------------------------------------------------------------------
__global__ __launch_bounds__(256)
void attn_mfma(const short* __restrict__ qd, const short* __restrict__ kd,
               const short* __restrict__ vTg, const short* __restrict__ mbf,
               short* __restrict__ abf) {
    __shared__ short qs[8192];   // 128 n-rows x 64 c (8 chunks)
    __shared__ short ks[4096];   //  64 m-rows x 64 c (8 chunks)
    __shared__ short vt[4096];   //  64 d-rows x 64 m (8 chunks)
    __shared__ short ss[8192];   // 128 n-rows x 64 m (8 chunks, wave-private rows)
    __shared__ short ms[8192];   // 128 n-rows x 64 m mask tile (bf16, same swizzle)

    const int tid = threadIdx.x;
    const int bh = blockIdx.x;                // swizzled: bh on x
    const int b = bh >> 3, h = bh & 7;
    const int n0 = blockIdx.y * 128;

    const int wave = tid >> 6, lane = tid & 63;
    const int quad = lane >> 4, l16 = lane & 15;

    const short* Qb = qd + ((size_t)b * Nn + n0) * Cc + h * Dd;        // stride Cc
    const short* Kb = kd + (size_t)b * Nn * Cc + h * Dd;               // stride Cc
    const short* Vb = vTg + ((size_t)b * Cc + h * Dd) * Nn;            // stride Nn
    const short* Mb = mbf + (size_t)n0 * Nn;                           // stride Nn

    stage_tile(qs, Qb, Cc, tid, 8, 1024);
    __syncthreads();                          // qs resident (vmcnt drained)
    short8 aT[2][2];                          // Q-frags (B-operand of S^T mfma)
    #pragma unroll
    for (int t = 0; t < 2; t++) {
        aT[t][0] = fragT(qs, 8, wave * 32 + t * 16 + l16, quad);
        aT[t][1] = fragT(qs, 8, wave * 32 + t * 16 + l16, 4 + quad);
    }

    float dreg[2] = {0.f, 0.f};               // partial denom for n-row = l16 (per t)
    floatx4 nacc[2][4];
    #pragma unroll
    for (int t = 0; t < 2; t++)
        #pragma unroll
        for (int i = 0; i < 4; i++) nacc[t][i] = (floatx4){0.f, 0.f, 0.f, 0.f};

    const int ssrow[2] = { wave * 32 + l16, wave * 32 + 16 + l16 };

    for (int m0 = 0; m0 < Nn; m0 += 64) {
        __syncthreads();                      // prior chunk's readers done
        stage_tile(ks, Kb + (size_t)m0 * Cc, Cc, tid, 8, 512);
        stage_tile(vt, Vb + m0, Nn, tid, 8, 512);
        stage_tile(ms, Mb + m0, Nn, tid, 8, 1024);   // mask tile, async DMA
        __syncthreads();                      // staged data visible

        // phase A: S^T = K Q^T; C: col=l16=n, row=quad*4+r=m
        #pragma unroll
        for (int mt = 0; mt < 4; mt++) {
            const short8 k0f = fragT(ks, 8, mt * 16 + l16, quad);
            const short8 k1f = fragT(ks, 8, mt * 16 + l16, 4 + quad);
            #pragma unroll
            for (int t = 0; t < 2; t++) {
                floatx4 s = (floatx4){0.f, 0.f, 0.f, 0.f};
                s = __builtin_amdgcn_mfma_f32_16x16x32_bf16(k0f, aT[t][0], s, 0, 0, 0);
                s = __builtin_amdgcn_mfma_f32_16x16x32_bf16(k1f, aT[t][1], s, 0, 0, 0);
                const int row = ssrow[t];
                const int c = mt * 16 + quad * 4;
                const int off = (row * 8 + ((c >> 3) ^ (row & 7))) * 8 + (c & 7);
                union { short h[4]; int2 v; } mk;
                mk.v = *(const int2*)&ms[off];          // ds_read_b64, no VMEM
                float sv0 = s[0] * bf2f(mk.h[0]);
                float sv1 = s[1] * bf2f(mk.h[1]);
                float sv2 = s[2] * bf2f(mk.h[2]);
                float sv3 = s[3] * bf2f(mk.h[3]);
                dreg[t] += (sv0 + sv1) + (sv2 + sv3);
                union { short h[4]; int2 v; } pk;
                pk.h[0] = f2bf(sv0); pk.h[1] = f2bf(sv1);
                pk.h[2] = f2bf(sv2); pk.h[3] = f2bf(sv3);
                *(int2*)&ss[off] = pk.v;                // ds_write_b64
            }
        }
        // no barrier: each wave reads exactly the ss rows it wrote
        // (within-wave in-order LDS + compiler lgkmcnt suffices)

        // phase B: num += P @ V.  V-frags shared across both n-tiles.
        short8 p[2][2];
        #pragma unroll
        for (int t = 0; t < 2; t++) {
            p[t][0] = fragT(ss, 8, wave * 32 + t * 16 + l16, quad);
            p[t][1] = fragT(ss, 8, wave * 32 + t * 16 + l16, 4 + quad);
        }
        #pragma unroll
        for (int dt = 0; dt < 4; dt++) {
            const short8 v0 = fragT(vt, 8, dt * 16 + l16, quad);
            const short8 v1 = fragT(vt, 8, dt * 16 + l16, 4 + quad);
            #pragma unroll
            for (int t = 0; t < 2; t++) {
                nacc[t][dt] = __builtin_amdgcn_mfma_f32_16x16x32_bf16(p[t][0], v0, nacc[t][dt], 0, 0, 0);
                nacc[t][dt] = __builtin_amdgcn_mfma_f32_16x16x32_bf16(p[t][1], v1, nacc[t][dt], 0, 0, 0);
            }
        }
    }

    // denom: cross-quad reduce (lanes sharing l16), then per-lane broadcast
    #pragma unroll
    for (int t = 0; t < 2; t++) {
        dreg[t] += __shfl_xor(dreg[t], 16, 64);
        dreg[t] += __shfl_xor(dreg[t], 32, 64);
    }

    #pragma unroll
    for (int t = 0; t < 2; t++)
        #pragma unroll
        for (int r = 0; r < 4; r++) {
            int nloc = quad * 4 + r;          // n within this 16-tile
            float den = __shfl(dreg[t], nloc, 64);
            int n = n0 + wave * 32 + t * 16 + nloc;
            float zr = 1.0f / (den + EPSF);
            #pragma unroll
            for (int dt = 0; dt < 4; dt++) {
                size_t o = ((size_t)b * Nn + n) * Cc + h * Dd + dt * 16 + l16;
                abf[o] = f2bf(nacc[t][dt][r] * zr);
            }
        }
}

// ---------------------------------------------------------------------------
// Output GEMM (single bf16 pass): out = A@W^T + bias (fp32 accumulate).
// BK=64 (r12 BK=128 regressed).  24 KB LDS.
// ---------------------------------------------------------------------------
__global__ __launch_bounds__(256)
void gemm_out(const short* __restrict__ abf, const short* __restrict__ woT,
              const float* __restrict__ bias, float* __restrict__ out) {
    __shared__ short smem[12288];      // 24 KB
    short* As = smem;                  // 64x64
    short* Bs = smem + 4096;           // 128x64

    const int tid = threadIdx.x;
    const int m0 = blockIdx.y * 64;
    const int n0 = blockIdx.x * 128;
    const int wave = tid >> 6, lane = tid & 63;
    const int quad = lane >> 4, l16 = lane & 15;
    const int wm = (wave >> 1) * 32, wn = (wave & 1) * 64;

    floatx4 acc[2][4];
    #pragma unroll
    for (int i = 0; i < 2; i++)
        #pragma unroll
        for (int j = 0; j < 4; j++) acc[i][j] = (floatx4){0.f, 0.f, 0.f, 0.f};

    const short* Ab = abf + (size_t)m0 * 512;
    const short* Bb = woT + (size_t)n0 * 512;

    for (int k0 = 0; k0 < 512; k0 += 64) {
        __syncthreads();
        stage_tile(As, Ab + k0, 512, tid, 8, 512);
        stage_tile(Bs, Bb + k0, 512, tid, 8, 1024);
        __syncthreads();
        #pragma unroll
        for (int kh = 0; kh < 2; kh++) {
            short8 a[2], b[4];
            #pragma unroll
            for (int i = 0; i < 2; i++)
                a[i] = fragT(As, 8, wm + i * 16 + l16, kh * 4 + quad);
            #pragma unroll
            for (int i = 0; i < 4; i++)
                b[i] = fragT(Bs, 8, wn + i * 16 + l16, kh * 4 + quad);
            #pragma unroll
            for (int mi = 0; mi < 2; mi++)
                #pragma unroll
                for (int ni = 0; ni < 4; ni++)
                    acc[mi][ni] = __builtin_amdgcn_mfma_f32_16x16x32_bf16(
                        a[mi], b[ni], acc[mi][ni], 0, 0, 0);
        }
    }

    #pragma unroll
    for (int mi = 0; mi < 2; mi++)
        #pragma unroll
        for (int r = 0; r < 4; r++) {
            int m = m0 + wm + mi * 16 + quad * 4 + r;
            #pragma unroll
            for (int ni = 0; ni < 4; ni++) {
                int n = n0 + wn + ni * 16 + l16;
                out[(size_t)m * 512 + n] = acc[mi][ni][r] + bias[n];
            }
        }
}

// ---------------------------------------------------------------------------
extern "C" void kernel_launch(void* const* d_in, const int* in_sizes, int n_in,
                              void* d_out, int out_size, void* d_ws, size_t ws_size,
                              hipStream_t stream) {
    const float* x     = (const float*)d_in[0];
    const float* mask  = (const float*)d_in[1];
    const float* w_qkv = (const float*)d_in[2];
    const float* w_out = (const float*)d_in[3];
    const float* b_out = (const float*)d_in[4];
    float* out = (float*)d_out;

    char* p = (char*)d_ws;
    short* xb  = (short*)p; p += 8388608;      // [8192][512]
    short* wqT = (short*)p; p += 1572864;      // [1536][512]
    short* Ad  = (short*)p; p += 2097152;      // [1024][1024]
    short* woT = (short*)p; p += 524288;       // [512][512]
    short* mbf = (short*)p; p += 2097152;      // [1024][1024] bf16 mask
    short* qT  = (short*)p; p += 8388608;      // [b][512][1024]
    short* kT  = (short*)p; p += 8388608;
    short* vT  = (short*)p; p += 8388608;
    short* qd  = (short*)p; p += 8388608;      // [b][1024][512]
    short* kd  = (short*)p; p += 8388608;
    short* abf = (short*)p; p += 8388608;      // [8192][512] attn out bf16

    dim3 blk(256);

    prep_all  <<<3072, blk, 0, stream>>>(x, mask, w_qkv, w_out,
                                         xb, Ad, wqT, woT, mbf);
    gemm_qkv  <<<dim3(64, 12), blk, 0, stream>>>(xb, wqT, qT, kT, vT);
    gemm_diff <<<dim3(16, 4, 8), blk, 0, stream>>>(Ad, qT, kT, qd, kd);
    attn_mfma <<<dim3(64, 8),  blk, 0, stream>>>(qd, kd, vT, mbf, abf);
    gemm_out  <<<dim3(4, 128), blk, 0, stream>>>(abf, woT, b_out, out);
}